// Round 11
// baseline (433.716 us; speedup 1.0000x reference)
//
#include <hip/hip_runtime.h>
#include <hip/hip_bf16.h>

#define B_ 8
#define L_ 2048
#define D_ 256
#define BK 32
#define KSPLIT 2
#define KQ (L_/KSPLIT)         // 1024 keys per split
#define NIT (KQ/BK)            // 32 iterations
#define PSTR 40
#define NROW (B_*L_)           // 16384
#define NE ((size_t)B_*L_*D_)  // 4194304
#define THR 13.0f              // defer-max threshold, log2 domain (~e^9), fp16-safe
#define MINIT (-1e30f)
#define LOG2E_F 1.44269504f

typedef __attribute__((ext_vector_type(8))) _Float16 f16x8;
typedef __attribute__((ext_vector_type(4))) _Float16 hf4;
typedef __attribute__((ext_vector_type(4))) float f32x4;

#define MFMA16F(a,b,c) __builtin_amdgcn_mfma_f32_16x16x32_f16((a),(b),(c),0,0,0)
#define NEG_INF (-__builtin_inff())
#define GLL(src,dst) __builtin_amdgcn_global_load_lds( \
    (const __attribute__((address_space(1))) void*)(src), \
    (__attribute__((address_space(3))) void*)(dst), 16, 0, 0)

__device__ __forceinline__ f32x4 fmax4(f32x4 a, f32x4 b){
  f32x4 r;
  r[0]=fmaxf(a[0],b[0]); r[1]=fmaxf(a[1],b[1]);
  r[2]=fmaxf(a[2],b[2]); r[3]=fmaxf(a[3],b[3]);
  return r;
}

// ---- prep v2 (r8): fp32 x -> fp16 x16 + vtl (pre-tiled swizzled V^T) ----
__global__ void prep_k(const float* __restrict__ x,
                       _Float16* __restrict__ x16,
                       _Float16* __restrict__ vtl){
  __shared__ _Float16 T[32][258];
  const int t = threadIdx.x;
  const int tIdx = blockIdx.x;          // 32-key tile, 0..63
  const int b = blockIdx.y;
  const int l0 = tIdx*32;

  #pragma unroll
  for (int i=0;i<4;++i){
    const int n8 = t + 256*i;
    const int row = n8>>5;
    const int c   = (n8&31)*8;
    size_t idx = ((size_t)(b*L_ + l0 + row))*D_ + c;
    float4 v0 = *(const float4*)(x + idx);
    float4 v1 = *(const float4*)(x + idx + 4);
    f16x8 h;
    h[0]=(_Float16)v0.x; h[1]=(_Float16)v0.y; h[2]=(_Float16)v0.z; h[3]=(_Float16)v0.w;
    h[4]=(_Float16)v1.x; h[5]=(_Float16)v1.y; h[6]=(_Float16)v1.z; h[7]=(_Float16)v1.w;
    *(f16x8*)(x16 + idx) = h;
    *(f16x8*)(&T[row][c]) = h;
  }
  __syncthreads();

  _Float16* vb = vtl + ((size_t)(b*64 + tIdx))*8192;
  #pragma unroll
  for (int i=0;i<4;++i){
    const int q = t + 256*i;
    const int d = q>>2, ph = q&3;
    const int kc = ph ^ ((d>>1)&3);
    const int k0 = kc*8;
    f16x8 h;
    #pragma unroll
    for (int j=0;j<8;++j) h[j] = T[k0+j][d];
    *(f16x8*)(vb + (size_t)q*8) = h;
  }
}

// ---- flash: QBLK=16, one-tile P/V pipeline, d-split PV across wave pairs ----
// QK unchanged: wave w owns q-rows [w*16, w*16+16) (16 K-frag reads).
// PV split: waves pair as {2a, 2a+1}; wave 2a+p computes BOTH groups'
// outputs for d-half p only -> V-frag reads per wave drop 16 -> 8 (the
// 4 waves previously read identical V fragments; this removes half that
// amplification on the ~78%-busy LDS pipe). O[0..7] = group ga, half p;
// O[8..15] = group ga+1, half p. A group's defer-max rescale is broadcast
// to the buddy wave via a parity-double-buffered LDS flag + sc[16], applied
// before the next PV accumulate (exactly where the math requires it).
__launch_bounds__(256, 2)
__global__ void flash_k(const _Float16* __restrict__ x16,
                        const _Float16* __restrict__ vtl,
                        const int* __restrict__ mask,
                        _Float16* __restrict__ oall,
                        float* __restrict__ mll,
                        float* __restrict__ mm){
  __shared__ __attribute__((aligned(16))) _Float16 sK[2][8192];     // 32 KB
  __shared__ __attribute__((aligned(16))) _Float16 sV[2][8192];     // 32 KB
  __shared__ __attribute__((aligned(16))) _Float16 sP[2][4][16*PSTR];// 10 KB
  __shared__ int   sFl[2][4];
  __shared__ float sSc[2][4][16];

  const int tid  = threadIdx.x;
  const int wave = tid >> 6, lane = tid & 63;
  const int quad = lane >> 4, l16 = lane & 15;
  const int b = blockIdx.y, z = blockIdx.z;
  const int q0w = blockIdx.x*64 + wave*16;
  const int sw = l16 & 7, vsw = (l16>>1)&3;
  const int p  = wave & 1;            // d-half owned for PV
  const int ga = wave & 2;            // PV group pair base {ga, ga+1}
  const int og = ga + (p^1);          // buddy-owned group (our other O half)

  f16x8 qh[8];
  {
    const _Float16* qr = x16 + ((size_t)(b*L_ + q0w + l16))*D_;
    const _Float16 l2e = (_Float16)LOG2E_F;
    #pragma unroll
    for (int ks=0; ks<8; ++ks){
      f16x8 h = *(const f16x8*)(qr + ks*32 + quad*8);
      #pragma unroll
      for (int j=0;j<8;++j) h[j] = h[j] * l2e;   // log2-domain scores
      qh[ks] = h;
    }
  }
  unsigned long long mb = 0;
  {
    const int* mrow = mask + b*L_ + z*KQ;
    #pragma unroll
    for (int j=0;j<64;++j)
      mb |= (unsigned long long)(mrow[j*16 + l16] ? 1u : 0u) << j;
  }

  f32x4 M = (f32x4){MINIT, MINIT, MINIT, MINIT};

  unsigned kof[4], vof[4], dof[4];
  #pragma unroll
  for (int i=0;i<4;++i){
    int c = (wave + i*4)*64 + lane;
    int r = c>>5, pk = c&31;
    kof[i] = (unsigned)(r*512 + ((pk ^ (r&7))*16));
    vof[i] = (unsigned)(c*16);
    dof[i] = (unsigned)((wave + i*4)*1024);
  }
  const char* kbase = (const char*)x16 + ((size_t)b*L_ + (size_t)z*KQ)*(D_*2);
  const char* vbase = (const char*)vtl + ((size_t)(b*64 + z*32))*16384;

  // prologue: K_0 only (V_0 staged at top of iter 0)
  #pragma unroll
  for (int i=0;i<4;++i) GLL(kbase + kof[i], (char*)sK[0] + dof[i]);

  f32x4 O[16], Osum;
  #pragma unroll
  for (int i=0;i<16;i++) O[i] = (f32x4){0.f,0.f,0.f,0.f};
  Osum = (f32x4){0.f,0.f,0.f,0.f};
  f16x8 ones;
  #pragma unroll
  for (int j=0;j<8;++j) ones[j] = (_Float16)1.0f;

  __syncthreads();   // K_0 visible

  for (int it=0; it<NIT; ++it){
    // ---- stage K_{t+1} and V_t ----
    if (it+1 < NIT){
      const char* kb2 = kbase + (size_t)(it+1)*16384;
      char* kd = (char*)sK[(it+1)&1];
      #pragma unroll
      for (int i=0;i<4;++i) GLL(kb2 + kof[i], kd + dof[i]);
    }
    {
      const char* vb2 = vbase + (size_t)it*16384;
      char* vd = (char*)sV[it&1];
      #pragma unroll
      for (int i=0;i<4;++i) GLL(vb2 + vof[i], vd + dof[i]);
    }
    const _Float16* kb = sK[it&1];

    // ---- S = Q·K^T (tile t, log2 domain) ----
    f32x4 S[2];
    S[0]=(f32x4){0,0,0,0}; S[1]=(f32x4){0,0,0,0};
    #pragma unroll
    for (int ks=0; ks<8; ++ks){
      f16x8 b0 = *(const f16x8*)(kb + (     l16)*256 + (((ks*4+quad)^sw)*8));
      f16x8 b1 = *(const f16x8*)(kb + (16 + l16)*256 + (((ks*4+quad)^sw)*8));
      S[0] = MFMA16F(qh[ks], b0, S[0]);
      S[1] = MFMA16F(qh[ks], b1, S[1]);
    }

    // ---- PV (tile t-1): apply buddy-group rescale (if signaled last
    //      iter), then accumulate both groups x own d-half ----
    if (it > 0){
      if (sFl[(it-1)&1][og]){
        f32x4 bs;
        #pragma unroll
        for (int r=0;r<4;++r) bs[r] = sSc[(it-1)&1][og][quad*4+r];
        #pragma unroll
        for (int lvt=0; lvt<8; ++lvt){
          const int oi = p ? lvt : 8+lvt;   // buddy group's half lives opposite
          #pragma unroll
          for (int r=0;r<4;++r) O[oi][r] *= bs[r];
        }
      }
      const _Float16* vb = sV[(it-1)&1];
      f16x8 pf0 = *(const f16x8*)(&sP[(it-1)&1][ga  ][l16*PSTR + quad*8]);
      f16x8 pf1 = *(const f16x8*)(&sP[(it-1)&1][ga+1][l16*PSTR + quad*8]);
      #pragma unroll
      for (int lvt=0; lvt<8; ++lvt){
        f16x8 bv = *(const f16x8*)(vb + (((p*8+lvt)*16)+l16)*32 + ((quad^vsw)*8));
        O[lvt]   = MFMA16F(pf0, bv, O[lvt]);     // group ga,   half p
        O[8+lvt] = MFMA16F(pf1, bv, O[8+lvt]);   // group ga+1, half p
      }
      Osum = MFMA16F(p ? pf1 : pf0, ones, Osum); // own group's row-sums
    }

    // ---- diag zero, then key padding mask ----
    {
      const int d0 = q0w - (z*KQ + it*BK);
      if ((unsigned)d0 < 32u){
        const int ntd = d0 >> 4;
        #pragma unroll
        for (int r=0;r<4;++r)
          S[ntd][r] = (l16 == quad*4+r) ? 0.0f : S[ntd][r];
      }
    }
    {
      const unsigned mw = (unsigned)(mb >> (unsigned)(it*2));
      const float mk0 = (mw & 1u) ? NEG_INF : 0.0f;
      const float mk1 = (mw & 2u) ? NEG_INF : 0.0f;
      #pragma unroll
      for (int r=0;r<4;++r){ S[0][r] += mk0; S[1][r] += mk1; }
    }

    // ---- defer-max check; own-half rescale + broadcast to buddy ----
    {
      f32x4 t = fmax4(S[0], S[1]);
      int ok = 1;
      #pragma unroll
      for (int r=0;r<4;++r) ok &= (t[r] <= M[r] + THR);
      if (!__all(ok)){
        #pragma unroll
        for (int off=1; off<16; off<<=1){
          f32x4 o;
          o[0]=__shfl_xor(t[0],off); o[1]=__shfl_xor(t[1],off);
          o[2]=__shfl_xor(t[2],off); o[3]=__shfl_xor(t[3],off);
          t = fmax4(t,o);
        }
        f32x4 mn = fmax4(M, t);
        float sc[4];
        #pragma unroll
        for (int r=0;r<4;++r) sc[r] = exp2f(M[r] - mn[r]);
        #pragma unroll
        for (int lvt=0; lvt<8; ++lvt){
          const int oi = p ? 8+lvt : lvt;   // own group's half
          #pragma unroll
          for (int r=0;r<4;++r) O[oi][r] *= sc[r];
        }
        #pragma unroll
        for (int r=0;r<4;++r) Osum[r] *= sc[r];
        M = mn;
        if (l16 == 0){
          #pragma unroll
          for (int r=0;r<4;++r) sSc[it&1][wave][quad*4+r] = sc[r];
        }
        if (lane == 0) sFl[it&1][wave] = 1;
      } else {
        if (lane == 0) sFl[it&1][wave] = 0;
      }
    }

    // ---- P = 2^(S - M) -> sP[t&1]; consumed next iteration ----
    #pragma unroll
    for (int r=0;r<4;++r){
      const int row = quad*4 + r;
      sP[it&1][wave][row*PSTR +      l16] = (_Float16)exp2f(S[0][r] - M[r]);
      sP[it&1][wave][row*PSTR + 16 + l16] = (_Float16)exp2f(S[1][r] - M[r]);
    }

    __syncthreads();   // sP/sV/sFl/sSc(t) visible for t+1; staging drained
  }

  // ---- drain: PV for the last tile (same buddy-rescale protocol) ----
  {
    if (sFl[(NIT-1)&1][og]){
      f32x4 bs;
      #pragma unroll
      for (int r=0;r<4;++r) bs[r] = sSc[(NIT-1)&1][og][quad*4+r];
      #pragma unroll
      for (int lvt=0; lvt<8; ++lvt){
        const int oi = p ? lvt : 8+lvt;
        #pragma unroll
        for (int r=0;r<4;++r) O[oi][r] *= bs[r];
      }
    }
    const _Float16* vb = sV[(NIT-1)&1];
    f16x8 pf0 = *(const f16x8*)(&sP[(NIT-1)&1][ga  ][l16*PSTR + quad*8]);
    f16x8 pf1 = *(const f16x8*)(&sP[(NIT-1)&1][ga+1][l16*PSTR + quad*8]);
    #pragma unroll
    for (int lvt=0; lvt<8; ++lvt){
      f16x8 bv = *(const f16x8*)(vb + (((p*8+lvt)*16)+l16)*32 + ((quad^vsw)*8));
      O[lvt]   = MFMA16F(pf0, bv, O[lvt]);
      O[8+lvt] = MFMA16F(pf1, bv, O[8+lvt]);
    }
    Osum = MFMA16F(p ? pf1 : pf0, ones, Osum);
  }

  // ---- epilogue: same oall format; each wave writes its d-half of the
  //      pair's two groups; own-group (m,l) as before ----
  {
    const int ub = b*(L_/16) + blockIdx.x*4;
    _Float16* ob0 = oall + (size_t)z*NE + (size_t)(ub+ga  )*4096;
    _Float16* ob1 = oall + (size_t)z*NE + (size_t)(ub+ga+1)*4096;
    #pragma unroll
    for (int lvt=0; lvt<8; ++lvt){
      hf4 h0, h1;
      #pragma unroll
      for (int r=0;r<4;++r){ h0[r] = (_Float16)O[lvt][r]; h1[r] = (_Float16)O[8+lvt][r]; }
      *(hf4*)(ob0 + (p*8+lvt)*256 + lane*4) = h0;
      *(hf4*)(ob1 + (p*8+lvt)*256 + lane*4) = h1;
    }
    if (l16 == 0){
      const int row = (ub + wave)*16 + quad*4;
      #pragma unroll
      for (int r=0;r<4;++r){
        mll[z*NROW + row + r] = Osum[r];
        mm [z*NROW + row + r] = M[r];        // log2 domain
      }
    }
  }
}

// ---- combine (r8): out = (sum_z 2^{m_z-m*} O'_z) / (sum_z 2^{m_z-m*} l_z) ----
__global__ void combine_k(float* __restrict__ out,
                          const _Float16* __restrict__ oall,
                          const float* __restrict__ mll,
                          const float* __restrict__ mm){
  __shared__ float T2[16][260];
  const int t = threadIdx.x, u = blockIdx.x;
  const int quad = (t>>4)&3, l16 = t&15;
  const int row0 = u*16 + quad*4;

  f32x4 mz[KSPLIT], lz[KSPLIT];
  #pragma unroll
  for (int zc=0; zc<KSPLIT; ++zc){
    mz[zc] = *(const f32x4*)(mm  + zc*NROW + row0);
    lz[zc] = *(const f32x4*)(mll + zc*NROW + row0);
  }
  f32x4 ms = mz[0];
  #pragma unroll
  for (int zc=1; zc<KSPLIT; ++zc) ms = fmax4(ms, mz[zc]);

  float sc[KSPLIT][4];
  f32x4 den = (f32x4){0.f,0.f,0.f,0.f};
  #pragma unroll
  for (int zc=0; zc<KSPLIT; ++zc){
    #pragma unroll
    for (int r=0;r<4;++r){
      sc[zc][r] = exp2f(mz[zc][r] - ms[r]);
      den[r] += sc[zc][r] * lz[zc][r];
    }
  }
  float inv[4];
  #pragma unroll
  for (int r=0;r<4;++r) inv[r] = 1.0f/den[r];

  #pragma unroll
  for (int i=0;i<4;++i){
    const int f = t + 256*i;
    const int vt = f>>6;
    float acc[4] = {0.f,0.f,0.f,0.f};
    #pragma unroll
    for (int zc=0; zc<KSPLIT; ++zc){
      hf4 v = *(const hf4*)(oall + (size_t)zc*NE + (size_t)u*4096 + (size_t)f*4);
      #pragma unroll
      for (int r=0;r<4;++r) acc[r] += sc[zc][r] * (float)v[r];
    }
    #pragma unroll
    for (int r=0;r<4;++r) T2[quad*4+r][vt*16+l16] = acc[r]*inv[r];
  }
  __syncthreads();
  #pragma unroll
  for (int p=0;p<4;++p){
    const int row = (t>>6) + p*4, col = (t&63)*4;
    float4 vv = *(const float4*)&T2[row][col];
    *(float4*)(out + ((size_t)u*16 + row)*D_ + col) = vv;
  }
}

extern "C" void kernel_launch(void* const* d_in, const int* in_sizes, int n_in,
                              void* d_out, int out_size, void* d_ws, size_t ws_size,
                              hipStream_t stream) {
  const float* x    = (const float*)d_in[0];
  const int*   mask = (const int*)d_in[1];
  float*       out  = (float*)d_out;

  _Float16* x16  = (_Float16*)d_ws;
  _Float16* vtl  = x16 + NE;
  _Float16* oall = vtl + NE;                       // KSPLIT*NE fp16
  float*    mll  = (float*)(oall + (size_t)KSPLIT*NE);
  float*    mm   = mll + (size_t)KSPLIT*NROW;

  prep_k   <<<dim3(L_/32, B_), dim3(256), 0, stream>>>(x, x16, vtl);
  flash_k  <<<dim3(L_/64, B_, KSPLIT), dim3(256), 0, stream>>>(x16, vtl, mask, oall, mll, mm);
  combine_k<<<dim3(NROW/16), dim3(256), 0, stream>>>(out, oall, mll, mm);
}

// Round 12
// 150.876 us; speedup vs baseline: 2.8747x; 2.8747x over previous
//
#include <hip/hip_runtime.h>
#include <hip/hip_bf16.h>

#define B_ 8
#define L_ 2048
#define D_ 256
#define BK 32
#define KSPLIT 2
#define KQ (L_/KSPLIT)         // 1024 keys per split
#define NIT (KQ/BK)            // 32 iterations
#define PSTR 40
#define NROW (B_*L_)           // 16384
#define NE ((size_t)B_*L_*D_)  // 4194304
#define THR 13.0f              // defer-max threshold, log2 domain (~e^9), fp16-safe
#define MINIT (-1e30f)
#define LOG2E_F 1.44269504f

typedef __attribute__((ext_vector_type(8))) _Float16 f16x8;
typedef __attribute__((ext_vector_type(4))) _Float16 hf4;
typedef __attribute__((ext_vector_type(4))) float f32x4;

#define MFMA16F(a,b,c) __builtin_amdgcn_mfma_f32_16x16x32_f16((a),(b),(c),0,0,0)
#define NEG_INF (-__builtin_inff())
#define GLL(src,dst) __builtin_amdgcn_global_load_lds( \
    (const __attribute__((address_space(1))) void*)(src), \
    (__attribute__((address_space(3))) void*)(dst), 16, 0, 0)

__device__ __forceinline__ f32x4 fmax4(f32x4 a, f32x4 b){
  f32x4 r;
  r[0]=fmaxf(a[0],b[0]); r[1]=fmaxf(a[1],b[1]);
  r[2]=fmaxf(a[2],b[2]); r[3]=fmaxf(a[3],b[3]);
  return r;
}

// ---- prep v2 (r8): fp32 x -> fp16 x16 + vtl (pre-tiled swizzled V^T) ----
__global__ void prep_k(const float* __restrict__ x,
                       _Float16* __restrict__ x16,
                       _Float16* __restrict__ vtl){
  __shared__ _Float16 T[32][258];
  const int t = threadIdx.x;
  const int tIdx = blockIdx.x;          // 32-key tile, 0..63
  const int b = blockIdx.y;
  const int l0 = tIdx*32;

  #pragma unroll
  for (int i=0;i<4;++i){
    const int n8 = t + 256*i;
    const int row = n8>>5;
    const int c   = (n8&31)*8;
    size_t idx = ((size_t)(b*L_ + l0 + row))*D_ + c;
    float4 v0 = *(const float4*)(x + idx);
    float4 v1 = *(const float4*)(x + idx + 4);
    f16x8 h;
    h[0]=(_Float16)v0.x; h[1]=(_Float16)v0.y; h[2]=(_Float16)v0.z; h[3]=(_Float16)v0.w;
    h[4]=(_Float16)v1.x; h[5]=(_Float16)v1.y; h[6]=(_Float16)v1.z; h[7]=(_Float16)v1.w;
    *(f16x8*)(x16 + idx) = h;
    *(f16x8*)(&T[row][c]) = h;
  }
  __syncthreads();

  _Float16* vb = vtl + ((size_t)(b*64 + tIdx))*8192;
  #pragma unroll
  for (int i=0;i<4;++i){
    const int q = t + 256*i;
    const int d = q>>2, ph = q&3;
    const int kc = ph ^ ((d>>1)&3);
    const int k0 = kc*8;
    f16x8 h;
    #pragma unroll
    for (int j=0;j<8;++j) h[j] = T[k0+j][d];
    *(f16x8*)(vb + (size_t)q*8) = h;
  }
}

// ---- flash: QBLK=16, one-tile P/V pipeline, d-split PV across wave pairs ----
// Same as r11 EXCEPT: all O[] rescale indices are compile-time constant
// inside wave-uniform if(p) branches (r11 used O[p?a:b] -> rule-#20 scratch
// spill, 1.25 GB WRITE). O[0..7] = group ga half p; O[8..15] = group ga+1
// half p. Own group's rows live at O[p?8..15:0..7] (own==ga+p).
__launch_bounds__(256, 2)
__global__ void flash_k(const _Float16* __restrict__ x16,
                        const _Float16* __restrict__ vtl,
                        const int* __restrict__ mask,
                        _Float16* __restrict__ oall,
                        float* __restrict__ mll,
                        float* __restrict__ mm){
  __shared__ __attribute__((aligned(16))) _Float16 sK[2][8192];     // 32 KB
  __shared__ __attribute__((aligned(16))) _Float16 sV[2][8192];     // 32 KB
  __shared__ __attribute__((aligned(16))) _Float16 sP[2][4][16*PSTR];// 10 KB
  __shared__ int   sFl[2][4];
  __shared__ float sSc[2][4][16];

  const int tid  = threadIdx.x;
  const int wave = tid >> 6, lane = tid & 63;
  const int quad = lane >> 4, l16 = lane & 15;
  const int b = blockIdx.y, z = blockIdx.z;
  const int q0w = blockIdx.x*64 + wave*16;
  const int sw = l16 & 7, vsw = (l16>>1)&3;
  const int p  = wave & 1;            // d-half owned for PV
  const int ga = wave & 2;            // PV group pair base {ga, ga+1}
  const int og = ga + (p^1);          // buddy-owned group (our other O half)

  f16x8 qh[8];
  {
    const _Float16* qr = x16 + ((size_t)(b*L_ + q0w + l16))*D_;
    const _Float16 l2e = (_Float16)LOG2E_F;
    #pragma unroll
    for (int ks=0; ks<8; ++ks){
      f16x8 h = *(const f16x8*)(qr + ks*32 + quad*8);
      #pragma unroll
      for (int j=0;j<8;++j) h[j] = h[j] * l2e;   // log2-domain scores
      qh[ks] = h;
    }
  }
  unsigned long long mb = 0;
  {
    const int* mrow = mask + b*L_ + z*KQ;
    #pragma unroll
    for (int j=0;j<64;++j)
      mb |= (unsigned long long)(mrow[j*16 + l16] ? 1u : 0u) << j;
  }

  f32x4 M = (f32x4){MINIT, MINIT, MINIT, MINIT};

  unsigned kof[4], vof[4], dof[4];
  #pragma unroll
  for (int i=0;i<4;++i){
    int c = (wave + i*4)*64 + lane;
    int r = c>>5, pk = c&31;
    kof[i] = (unsigned)(r*512 + ((pk ^ (r&7))*16));
    vof[i] = (unsigned)(c*16);
    dof[i] = (unsigned)((wave + i*4)*1024);
  }
  const char* kbase = (const char*)x16 + ((size_t)b*L_ + (size_t)z*KQ)*(D_*2);
  const char* vbase = (const char*)vtl + ((size_t)(b*64 + z*32))*16384;

  // prologue: K_0 only (V_0 staged at top of iter 0)
  #pragma unroll
  for (int i=0;i<4;++i) GLL(kbase + kof[i], (char*)sK[0] + dof[i]);

  f32x4 O[16], Osum;
  #pragma unroll
  for (int i=0;i<16;i++) O[i] = (f32x4){0.f,0.f,0.f,0.f};
  Osum = (f32x4){0.f,0.f,0.f,0.f};
  f16x8 ones;
  #pragma unroll
  for (int j=0;j<8;++j) ones[j] = (_Float16)1.0f;

  __syncthreads();   // K_0 visible

  for (int it=0; it<NIT; ++it){
    // ---- stage K_{t+1} and V_t ----
    if (it+1 < NIT){
      const char* kb2 = kbase + (size_t)(it+1)*16384;
      char* kd = (char*)sK[(it+1)&1];
      #pragma unroll
      for (int i=0;i<4;++i) GLL(kb2 + kof[i], kd + dof[i]);
    }
    {
      const char* vb2 = vbase + (size_t)it*16384;
      char* vd = (char*)sV[it&1];
      #pragma unroll
      for (int i=0;i<4;++i) GLL(vb2 + vof[i], vd + dof[i]);
    }
    const _Float16* kb = sK[it&1];

    // ---- S = Q·K^T (tile t, log2 domain) ----
    f32x4 S[2];
    S[0]=(f32x4){0,0,0,0}; S[1]=(f32x4){0,0,0,0};
    #pragma unroll
    for (int ks=0; ks<8; ++ks){
      f16x8 b0 = *(const f16x8*)(kb + (     l16)*256 + (((ks*4+quad)^sw)*8));
      f16x8 b1 = *(const f16x8*)(kb + (16 + l16)*256 + (((ks*4+quad)^sw)*8));
      S[0] = MFMA16F(qh[ks], b0, S[0]);
      S[1] = MFMA16F(qh[ks], b1, S[1]);
    }

    // ---- PV (tile t-1): buddy-group rescale (static idx), then MFMA ----
    if (it > 0){
      if (sFl[(it-1)&1][og]){
        f32x4 bs;
        #pragma unroll
        for (int r=0;r<4;++r) bs[r] = sSc[(it-1)&1][og][quad*4+r];
        if (p){          // buddy group = ga (lives in O[0..7])
          #pragma unroll
          for (int lvt=0; lvt<8; ++lvt)
            #pragma unroll
            for (int r=0;r<4;++r) O[lvt][r] *= bs[r];
        } else {         // buddy group = ga+1 (lives in O[8..15])
          #pragma unroll
          for (int lvt=0; lvt<8; ++lvt)
            #pragma unroll
            for (int r=0;r<4;++r) O[8+lvt][r] *= bs[r];
        }
      }
      const _Float16* vb = sV[(it-1)&1];
      f16x8 pf0 = *(const f16x8*)(&sP[(it-1)&1][ga  ][l16*PSTR + quad*8]);
      f16x8 pf1 = *(const f16x8*)(&sP[(it-1)&1][ga+1][l16*PSTR + quad*8]);
      #pragma unroll
      for (int lvt=0; lvt<8; ++lvt){
        f16x8 bv = *(const f16x8*)(vb + (((p*8+lvt)*16)+l16)*32 + ((quad^vsw)*8));
        O[lvt]   = MFMA16F(pf0, bv, O[lvt]);     // group ga,   half p
        O[8+lvt] = MFMA16F(pf1, bv, O[8+lvt]);   // group ga+1, half p
      }
      Osum = MFMA16F(p ? pf1 : pf0, ones, Osum); // own group's row-sums
    }

    // ---- diag zero, then key padding mask ----
    {
      const int d0 = q0w - (z*KQ + it*BK);
      if ((unsigned)d0 < 32u){
        const int ntd = d0 >> 4;
        #pragma unroll
        for (int r=0;r<4;++r)
          S[ntd][r] = (l16 == quad*4+r) ? 0.0f : S[ntd][r];
      }
    }
    {
      const unsigned mw = (unsigned)(mb >> (unsigned)(it*2));
      const float mk0 = (mw & 1u) ? NEG_INF : 0.0f;
      const float mk1 = (mw & 2u) ? NEG_INF : 0.0f;
      #pragma unroll
      for (int r=0;r<4;++r){ S[0][r] += mk0; S[1][r] += mk1; }
    }

    // ---- defer-max check; own-group rescale (static idx) + broadcast ----
    {
      f32x4 t = fmax4(S[0], S[1]);
      int ok = 1;
      #pragma unroll
      for (int r=0;r<4;++r) ok &= (t[r] <= M[r] + THR);
      if (!__all(ok)){
        #pragma unroll
        for (int off=1; off<16; off<<=1){
          f32x4 o;
          o[0]=__shfl_xor(t[0],off); o[1]=__shfl_xor(t[1],off);
          o[2]=__shfl_xor(t[2],off); o[3]=__shfl_xor(t[3],off);
          t = fmax4(t,o);
        }
        f32x4 mn = fmax4(M, t);
        float sc[4];
        #pragma unroll
        for (int r=0;r<4;++r) sc[r] = exp2f(M[r] - mn[r]);
        if (p){          // own group = ga+1 (lives in O[8..15])
          #pragma unroll
          for (int lvt=0; lvt<8; ++lvt)
            #pragma unroll
            for (int r=0;r<4;++r) O[8+lvt][r] *= sc[r];
        } else {         // own group = ga (lives in O[0..7])
          #pragma unroll
          for (int lvt=0; lvt<8; ++lvt)
            #pragma unroll
            for (int r=0;r<4;++r) O[lvt][r] *= sc[r];
        }
        #pragma unroll
        for (int r=0;r<4;++r) Osum[r] *= sc[r];
        M = mn;
        if (l16 == 0){
          #pragma unroll
          for (int r=0;r<4;++r) sSc[it&1][wave][quad*4+r] = sc[r];
        }
        if (lane == 0) sFl[it&1][wave] = 1;
      } else {
        if (lane == 0) sFl[it&1][wave] = 0;
      }
    }

    // ---- P = 2^(S - M) -> sP[t&1]; consumed next iteration ----
    #pragma unroll
    for (int r=0;r<4;++r){
      const int row = quad*4 + r;
      sP[it&1][wave][row*PSTR +      l16] = (_Float16)exp2f(S[0][r] - M[r]);
      sP[it&1][wave][row*PSTR + 16 + l16] = (_Float16)exp2f(S[1][r] - M[r]);
    }

    __syncthreads();   // sP/sV/sFl/sSc(t) visible for t+1; staging drained
  }

  // ---- drain: PV for the last tile (same protocol, static idx) ----
  {
    if (sFl[(NIT-1)&1][og]){
      f32x4 bs;
      #pragma unroll
      for (int r=0;r<4;++r) bs[r] = sSc[(NIT-1)&1][og][quad*4+r];
      if (p){
        #pragma unroll
        for (int lvt=0; lvt<8; ++lvt)
          #pragma unroll
          for (int r=0;r<4;++r) O[lvt][r] *= bs[r];
      } else {
        #pragma unroll
        for (int lvt=0; lvt<8; ++lvt)
          #pragma unroll
          for (int r=0;r<4;++r) O[8+lvt][r] *= bs[r];
      }
    }
    const _Float16* vb = sV[(NIT-1)&1];
    f16x8 pf0 = *(const f16x8*)(&sP[(NIT-1)&1][ga  ][l16*PSTR + quad*8]);
    f16x8 pf1 = *(const f16x8*)(&sP[(NIT-1)&1][ga+1][l16*PSTR + quad*8]);
    #pragma unroll
    for (int lvt=0; lvt<8; ++lvt){
      f16x8 bv = *(const f16x8*)(vb + (((p*8+lvt)*16)+l16)*32 + ((quad^vsw)*8));
      O[lvt]   = MFMA16F(pf0, bv, O[lvt]);
      O[8+lvt] = MFMA16F(pf1, bv, O[8+lvt]);
    }
    Osum = MFMA16F(p ? pf1 : pf0, ones, Osum);
  }

  // ---- epilogue: same oall format; wave writes its d-half of both groups ----
  {
    const int ub = b*(L_/16) + blockIdx.x*4;
    _Float16* ob0 = oall + (size_t)z*NE + (size_t)(ub+ga  )*4096;
    _Float16* ob1 = oall + (size_t)z*NE + (size_t)(ub+ga+1)*4096;
    #pragma unroll
    for (int lvt=0; lvt<8; ++lvt){
      hf4 h0, h1;
      #pragma unroll
      for (int r=0;r<4;++r){ h0[r] = (_Float16)O[lvt][r]; h1[r] = (_Float16)O[8+lvt][r]; }
      *(hf4*)(ob0 + (p*8+lvt)*256 + lane*4) = h0;
      *(hf4*)(ob1 + (p*8+lvt)*256 + lane*4) = h1;
    }
    if (l16 == 0){
      const int row = (ub + wave)*16 + quad*4;
      #pragma unroll
      for (int r=0;r<4;++r){
        mll[z*NROW + row + r] = Osum[r];
        mm [z*NROW + row + r] = M[r];        // log2 domain
      }
    }
  }
}

// ---- combine (r8): out = (sum_z 2^{m_z-m*} O'_z) / (sum_z 2^{m_z-m*} l_z) ----
__global__ void combine_k(float* __restrict__ out,
                          const _Float16* __restrict__ oall,
                          const float* __restrict__ mll,
                          const float* __restrict__ mm){
  __shared__ float T2[16][260];
  const int t = threadIdx.x, u = blockIdx.x;
  const int quad = (t>>4)&3, l16 = t&15;
  const int row0 = u*16 + quad*4;

  f32x4 mz[KSPLIT], lz[KSPLIT];
  #pragma unroll
  for (int zc=0; zc<KSPLIT; ++zc){
    mz[zc] = *(const f32x4*)(mm  + zc*NROW + row0);
    lz[zc] = *(const f32x4*)(mll + zc*NROW + row0);
  }
  f32x4 ms = mz[0];
  #pragma unroll
  for (int zc=1; zc<KSPLIT; ++zc) ms = fmax4(ms, mz[zc]);

  float sc[KSPLIT][4];
  f32x4 den = (f32x4){0.f,0.f,0.f,0.f};
  #pragma unroll
  for (int zc=0; zc<KSPLIT; ++zc){
    #pragma unroll
    for (int r=0;r<4;++r){
      sc[zc][r] = exp2f(mz[zc][r] - ms[r]);
      den[r] += sc[zc][r] * lz[zc][r];
    }
  }
  float inv[4];
  #pragma unroll
  for (int r=0;r<4;++r) inv[r] = 1.0f/den[r];

  #pragma unroll
  for (int i=0;i<4;++i){
    const int f = t + 256*i;
    const int vt = f>>6;
    float acc[4] = {0.f,0.f,0.f,0.f};
    #pragma unroll
    for (int zc=0; zc<KSPLIT; ++zc){
      hf4 v = *(const hf4*)(oall + (size_t)zc*NE + (size_t)u*4096 + (size_t)f*4);
      #pragma unroll
      for (int r=0;r<4;++r) acc[r] += sc[zc][r] * (float)v[r];
    }
    #pragma unroll
    for (int r=0;r<4;++r) T2[quad*4+r][vt*16+l16] = acc[r]*inv[r];
  }
  __syncthreads();
  #pragma unroll
  for (int p=0;p<4;++p){
    const int row = (t>>6) + p*4, col = (t&63)*4;
    float4 vv = *(const float4*)&T2[row][col];
    *(float4*)(out + ((size_t)u*16 + row)*D_ + col) = vv;
  }
}

extern "C" void kernel_launch(void* const* d_in, const int* in_sizes, int n_in,
                              void* d_out, int out_size, void* d_ws, size_t ws_size,
                              hipStream_t stream) {
  const float* x    = (const float*)d_in[0];
  const int*   mask = (const int*)d_in[1];
  float*       out  = (float*)d_out;

  _Float16* x16  = (_Float16*)d_ws;
  _Float16* vtl  = x16 + NE;
  _Float16* oall = vtl + NE;                       // KSPLIT*NE fp16
  float*    mll  = (float*)(oall + (size_t)KSPLIT*NE);
  float*    mm   = mll + (size_t)KSPLIT*NROW;

  prep_k   <<<dim3(L_/32, B_), dim3(256), 0, stream>>>(x, x16, vtl);
  flash_k  <<<dim3(L_/64, B_, KSPLIT), dim3(256), 0, stream>>>(x16, vtl, mask, oall, mll, mm);
  combine_k<<<dim3(NROW/16), dim3(256), 0, stream>>>(out, oall, mll, mm);
}

// Round 14
// 147.287 us; speedup vs baseline: 2.9447x; 1.0244x over previous
//
#include <hip/hip_runtime.h>
#include <hip/hip_bf16.h>

#define B_ 8
#define L_ 2048
#define D_ 256
#define BK 32
#define KSPLIT 2
#define KQ (L_/KSPLIT)         // 1024 keys per split
#define NIT (KQ/BK)            // 32 iterations
#define PSTR 40
#define NROW (B_*L_)           // 16384
#define NE ((size_t)B_*L_*D_)  // 4194304
#define THR 13.0f              // defer-max threshold, log2 domain: P <= 2^13.
                               // NOT 15: O partials are stored fp16; with P up
                               // to 2^15 the P·V row-sums overflow 65504 (r13
                               // absmax=inf). 2^13 leaves the needed headroom.
#define MINIT (-1e30f)
#define LOG2E_F 1.44269504f

typedef __attribute__((ext_vector_type(8))) _Float16 f16x8;
typedef __attribute__((ext_vector_type(4))) _Float16 hf4;
typedef __attribute__((ext_vector_type(4))) float f32x4;

#define MFMA16F(a,b,c) __builtin_amdgcn_mfma_f32_16x16x32_f16((a),(b),(c),0,0,0)
#define NEG_INF (-__builtin_inff())
#define GLL(src,dst) __builtin_amdgcn_global_load_lds( \
    (const __attribute__((address_space(1))) void*)(src), \
    (__attribute__((address_space(3))) void*)(dst), 16, 0, 0)

__device__ __forceinline__ f32x4 fmax4(f32x4 a, f32x4 b){
  f32x4 r;
  r[0]=fmaxf(a[0],b[0]); r[1]=fmaxf(a[1],b[1]);
  r[2]=fmaxf(a[2],b[2]); r[3]=fmaxf(a[3],b[3]);
  return r;
}

// ---- prep v2 (r8): fp32 x -> fp16 x16 + vtl (pre-tiled swizzled V^T) ----
__global__ void prep_k(const float* __restrict__ x,
                       _Float16* __restrict__ x16,
                       _Float16* __restrict__ vtl){
  __shared__ _Float16 T[32][258];
  const int t = threadIdx.x;
  const int tIdx = blockIdx.x;          // 32-key tile, 0..63
  const int b = blockIdx.y;
  const int l0 = tIdx*32;

  #pragma unroll
  for (int i=0;i<4;++i){
    const int n8 = t + 256*i;
    const int row = n8>>5;
    const int c   = (n8&31)*8;
    size_t idx = ((size_t)(b*L_ + l0 + row))*D_ + c;
    float4 v0 = *(const float4*)(x + idx);
    float4 v1 = *(const float4*)(x + idx + 4);
    f16x8 h;
    h[0]=(_Float16)v0.x; h[1]=(_Float16)v0.y; h[2]=(_Float16)v0.z; h[3]=(_Float16)v0.w;
    h[4]=(_Float16)v1.x; h[5]=(_Float16)v1.y; h[6]=(_Float16)v1.z; h[7]=(_Float16)v1.w;
    *(f16x8*)(x16 + idx) = h;
    *(f16x8*)(&T[row][c]) = h;
  }
  __syncthreads();

  _Float16* vb = vtl + ((size_t)(b*64 + tIdx))*8192;
  #pragma unroll
  for (int i=0;i<4;++i){
    const int q = t + 256*i;
    const int d = q>>2, ph = q&3;
    const int kc = ph ^ ((d>>1)&3);
    const int k0 = kc*8;
    f16x8 h;
    #pragma unroll
    for (int j=0;j<8;++j) h[j] = T[k0+j][d];
    *(f16x8*)(vb + (size_t)q*8) = h;
  }
}

// ---- flash (r5/r8 structure): QBLK=16, one-tile P/V pipeline, exp2 ----
// Iteration t: QK(t) -> PV(t-1) -> softmax(t) -> write sP[t&1] -> barrier.
// T5: s_setprio(1) around the QK/PV MFMA clusters (2 independent blocks/CU
// at different phases -> scheduler can favor the MFMA-entering wave).
__launch_bounds__(256, 2)
__global__ void flash_k(const _Float16* __restrict__ x16,
                        const _Float16* __restrict__ vtl,
                        const int* __restrict__ mask,
                        _Float16* __restrict__ oall,
                        float* __restrict__ mll,
                        float* __restrict__ mm){
  __shared__ __attribute__((aligned(16))) _Float16 sK[2][8192];     // 32 KB
  __shared__ __attribute__((aligned(16))) _Float16 sV[2][8192];     // 32 KB
  __shared__ __attribute__((aligned(16))) _Float16 sP[2][4][16*PSTR];// 10 KB

  const int tid  = threadIdx.x;
  const int wave = tid >> 6, lane = tid & 63;
  const int quad = lane >> 4, l16 = lane & 15;
  const int b = blockIdx.y, z = blockIdx.z;
  const int q0w = blockIdx.x*64 + wave*16;
  const int sw = l16 & 7, vsw = (l16>>1)&3;

  f16x8 qh[8];
  {
    const _Float16* qr = x16 + ((size_t)(b*L_ + q0w + l16))*D_;
    const _Float16 l2e = (_Float16)LOG2E_F;
    #pragma unroll
    for (int ks=0; ks<8; ++ks){
      f16x8 h = *(const f16x8*)(qr + ks*32 + quad*8);
      #pragma unroll
      for (int j=0;j<8;++j) h[j] = h[j] * l2e;   // log2-domain scores
      qh[ks] = h;
    }
  }
  unsigned long long mb = 0;
  {
    const int* mrow = mask + b*L_ + z*KQ;
    #pragma unroll
    for (int j=0;j<64;++j)
      mb |= (unsigned long long)(mrow[j*16 + l16] ? 1u : 0u) << j;
  }

  f32x4 M = (f32x4){MINIT, MINIT, MINIT, MINIT};

  unsigned kof[4], vof[4], dof[4];
  #pragma unroll
  for (int i=0;i<4;++i){
    int c = (wave + i*4)*64 + lane;
    int r = c>>5, pk = c&31;
    kof[i] = (unsigned)(r*512 + ((pk ^ (r&7))*16));
    vof[i] = (unsigned)(c*16);
    dof[i] = (unsigned)((wave + i*4)*1024);
  }
  const char* kbase = (const char*)x16 + ((size_t)b*L_ + (size_t)z*KQ)*(D_*2);
  const char* vbase = (const char*)vtl + ((size_t)(b*64 + z*32))*16384;

  // prologue: K_0 only (V_0 is staged at the top of iter 0)
  #pragma unroll
  for (int i=0;i<4;++i) GLL(kbase + kof[i], (char*)sK[0] + dof[i]);

  f32x4 O[16], Osum;
  #pragma unroll
  for (int i=0;i<16;i++) O[i] = (f32x4){0.f,0.f,0.f,0.f};
  Osum = (f32x4){0.f,0.f,0.f,0.f};
  f16x8 ones;
  #pragma unroll
  for (int j=0;j<8;++j) ones[j] = (_Float16)1.0f;

  __syncthreads();   // K_0 visible

  for (int it=0; it<NIT; ++it){
    // ---- stage K_{t+1} and V_t ----
    if (it+1 < NIT){
      const char* kb2 = kbase + (size_t)(it+1)*16384;
      char* kd = (char*)sK[(it+1)&1];
      #pragma unroll
      for (int i=0;i<4;++i) GLL(kb2 + kof[i], kd + dof[i]);
    }
    {
      const char* vb2 = vbase + (size_t)it*16384;
      char* vd = (char*)sV[it&1];
      #pragma unroll
      for (int i=0;i<4;++i) GLL(vb2 + vof[i], vd + dof[i]);
    }
    const _Float16* kb = sK[it&1];

    // ---- S = Q·K^T (tile t, log2 domain) ----
    f32x4 S[2];
    S[0]=(f32x4){0,0,0,0}; S[1]=(f32x4){0,0,0,0};
    __builtin_amdgcn_s_setprio(1);
    #pragma unroll
    for (int ks=0; ks<8; ++ks){
      f16x8 b0 = *(const f16x8*)(kb + (     l16)*256 + (((ks*4+quad)^sw)*8));
      f16x8 b1 = *(const f16x8*)(kb + (16 + l16)*256 + (((ks*4+quad)^sw)*8));
      S[0] = MFMA16F(qh[ks], b0, S[0]);
      S[1] = MFMA16F(qh[ks], b1, S[1]);
    }
    __builtin_amdgcn_s_setprio(0);

    // ---- PV (tile t-1): operands ready since last barrier ----
    if (it > 0){
      const _Float16* vb = sV[(it-1)&1];
      f16x8 pf = *(const f16x8*)(&sP[(it-1)&1][wave][l16*PSTR + quad*8]);
      __builtin_amdgcn_s_setprio(1);
      #pragma unroll
      for (int vt=0; vt<16; ++vt){
        f16x8 bv = *(const f16x8*)(vb + (vt*16+l16)*32 + ((quad^vsw)*8));
        O[vt] = MFMA16F(pf, bv, O[vt]);
      }
      Osum = MFMA16F(pf, ones, Osum);
      __builtin_amdgcn_s_setprio(0);
    }

    // ---- diag zero (score 0 -> log2 score 0), then key padding mask ----
    {
      const int d0 = q0w - (z*KQ + it*BK);
      if ((unsigned)d0 < 32u){
        const int ntd = d0 >> 4;
        #pragma unroll
        for (int r=0;r<4;++r)
          S[ntd][r] = (l16 == quad*4+r) ? 0.0f : S[ntd][r];
      }
    }
    {
      const unsigned mw = (unsigned)(mb >> (unsigned)(it*2));
      const float mk0 = (mw & 1u) ? NEG_INF : 0.0f;
      const float mk1 = (mw & 2u) ? NEG_INF : 0.0f;
      #pragma unroll
      for (int r=0;r<4;++r){ S[0][r] += mk0; S[1][r] += mk1; }
    }

    // ---- defer-max check; rescale covers all tiles < t (PV t-1 done) ----
    {
      f32x4 t = fmax4(S[0], S[1]);
      int ok = 1;
      #pragma unroll
      for (int r=0;r<4;++r) ok &= (t[r] <= M[r] + THR);
      if (!__all(ok)){
        #pragma unroll
        for (int off=1; off<16; off<<=1){
          f32x4 o;
          o[0]=__shfl_xor(t[0],off); o[1]=__shfl_xor(t[1],off);
          o[2]=__shfl_xor(t[2],off); o[3]=__shfl_xor(t[3],off);
          t = fmax4(t,o);
        }
        f32x4 mn = fmax4(M, t);
        float sc[4];
        #pragma unroll
        for (int r=0;r<4;++r) sc[r] = exp2f(M[r] - mn[r]);
        #pragma unroll
        for (int vt=0; vt<16; ++vt){
          #pragma unroll
          for (int r=0;r<4;++r) O[vt][r] *= sc[r];
        }
        #pragma unroll
        for (int r=0;r<4;++r) Osum[r] *= sc[r];
        M = mn;
      }
    }

    // ---- P = 2^(S - M) -> sP[t&1]; consumed next iteration ----
    #pragma unroll
    for (int r=0;r<4;++r){
      const int row = quad*4 + r;
      sP[it&1][wave][row*PSTR +      l16] = (_Float16)exp2f(S[0][r] - M[r]);
      sP[it&1][wave][row*PSTR + 16 + l16] = (_Float16)exp2f(S[1][r] - M[r]);
    }

    __syncthreads();   // sP/sV(t) visible for t+1; staging drained
  }

  // ---- drain: PV for the last tile ----
  {
    const _Float16* vb = sV[(NIT-1)&1];
    f16x8 pf = *(const f16x8*)(&sP[(NIT-1)&1][wave][l16*PSTR + quad*8]);
    __builtin_amdgcn_s_setprio(1);
    #pragma unroll
    for (int vt=0; vt<16; ++vt){
      f16x8 bv = *(const f16x8*)(vb + (vt*16+l16)*32 + ((quad^vsw)*8));
      O[vt] = MFMA16F(pf, bv, O[vt]);
    }
    Osum = MFMA16F(pf, ones, Osum);
    __builtin_amdgcn_s_setprio(0);
  }

  // ---- epilogue: fragment-major fp16 partial O' + partial l + running m ----
  {
    const int u = b*(L_/16) + blockIdx.x*4 + wave;
    _Float16* ob = oall + (size_t)z*NE + (size_t)u*4096;
    #pragma unroll
    for (int vt=0; vt<16; ++vt){
      hf4 hh;
      #pragma unroll
      for (int r=0;r<4;++r) hh[r] = (_Float16)O[vt][r];
      *(hf4*)(ob + vt*256 + lane*4) = hh;
    }
    if (l16 == 0){
      const int row = u*16 + quad*4;
      #pragma unroll
      for (int r=0;r<4;++r){
        mll[z*NROW + row + r] = Osum[r];
        mm [z*NROW + row + r] = M[r];        // log2 domain
      }
    }
  }
}

// ---- combine: out = (sum_z 2^{m_z-m*} O'_z) / (sum_z 2^{m_z-m*} l_z) ----
__global__ void combine_k(float* __restrict__ out,
                          const _Float16* __restrict__ oall,
                          const float* __restrict__ mll,
                          const float* __restrict__ mm){
  __shared__ float T2[16][260];
  const int t = threadIdx.x, u = blockIdx.x;
  const int quad = (t>>4)&3, l16 = t&15;
  const int row0 = u*16 + quad*4;

  f32x4 mz[KSPLIT], lz[KSPLIT];
  #pragma unroll
  for (int zc=0; zc<KSPLIT; ++zc){
    mz[zc] = *(const f32x4*)(mm  + zc*NROW + row0);
    lz[zc] = *(const f32x4*)(mll + zc*NROW + row0);
  }
  f32x4 ms = mz[0];
  #pragma unroll
  for (int zc=1; zc<KSPLIT; ++zc) ms = fmax4(ms, mz[zc]);

  float sc[KSPLIT][4];
  f32x4 den = (f32x4){0.f,0.f,0.f,0.f};
  #pragma unroll
  for (int zc=0; zc<KSPLIT; ++zc){
    #pragma unroll
    for (int r=0;r<4;++r){
      sc[zc][r] = exp2f(mz[zc][r] - ms[r]);
      den[r] += sc[zc][r] * lz[zc][r];
    }
  }
  float inv[4];
  #pragma unroll
  for (int r=0;r<4;++r) inv[r] = 1.0f/den[r];

  #pragma unroll
  for (int i=0;i<4;++i){
    const int f = t + 256*i;
    const int vt = f>>6;
    float acc[4] = {0.f,0.f,0.f,0.f};
    #pragma unroll
    for (int zc=0; zc<KSPLIT; ++zc){
      hf4 v = *(const hf4*)(oall + (size_t)zc*NE + (size_t)u*4096 + (size_t)f*4);
      #pragma unroll
      for (int r=0;r<4;++r) acc[r] += sc[zc][r] * (float)v[r];
    }
    #pragma unroll
    for (int r=0;r<4;++r) T2[quad*4+r][vt*16+l16] = acc[r]*inv[r];
  }
  __syncthreads();
  #pragma unroll
  for (int p=0;p<4;++p){
    const int row = (t>>6) + p*4, col = (t&63)*4;
    float4 vv = *(const float4*)&T2[row][col];
    *(float4*)(out + ((size_t)u*16 + row)*D_ + col) = vv;
  }
}

extern "C" void kernel_launch(void* const* d_in, const int* in_sizes, int n_in,
                              void* d_out, int out_size, void* d_ws, size_t ws_size,
                              hipStream_t stream) {
  const float* x    = (const float*)d_in[0];
  const int*   mask = (const int*)d_in[1];
  float*       out  = (float*)d_out;

  _Float16* x16  = (_Float16*)d_ws;
  _Float16* vtl  = x16 + NE;
  _Float16* oall = vtl + NE;                       // KSPLIT*NE fp16
  float*    mll  = (float*)(oall + (size_t)KSPLIT*NE);
  float*    mm   = mll + (size_t)KSPLIT*NROW;

  prep_k   <<<dim3(L_/32, B_), dim3(256), 0, stream>>>(x, x16, vtl);
  flash_k  <<<dim3(L_/64, B_, KSPLIT), dim3(256), 0, stream>>>(x16, vtl, mask, oall, mll, mm);
  combine_k<<<dim3(NROW/16), dim3(256), 0, stream>>>(out, oall, mll, mm);
}